// Round 2
// baseline (225.688 us; speedup 1.0000x reference)
//
#include <hip/hip_runtime.h>

// HierarchicalRouter: x[16384,2048] fp32, group_gate_w[8,2048], expert_gate_w[64,2048]
// out = concat(valid_mask[16384,64] as 0/1 float, normalized_weights[16384,64])
//
// R6: two-kernel structure.
//  prep (640x256): splits W (80 gates: 64 expert + 8 group + 8 zero-pad) into f16
//    h/l planes (v = h + l/2048), laid out in mfma_f32_16x16x32_f16 A-fragment lane
//    order: half index ((g*64 + ks)*64 + (q*16 + m))*8 + j  for W[g*16+m][ks*32+q*8+j].
//    655 KB into d_ws (poison-fill shows ws = 512 MiB). Coalesced 2B writes.
//  router (1024x256): 16 tokens/block, wave w = K-quarter (512 k each). NO LDS and NO
//    barriers in the K-loop: x B-fragments loaded directly from global (128B/row
//    segments), split in-reg; W A-fragments loaded from ws (1KB/wave coalesced,
//    L2-resident). 15 MFMAs per k-step, 240 per wave. logit = accH + accC/2048
//    (exact-split, proven R4/R5 numerics). LDS = 20.7 KB epilogue only -> 4 blocks/CU,
//    16 waves/CU, whole grid co-resident. Epilogue: 4-way K-reduce (3 barriers),
//    softmax 4 tokens/wave (proven fp32 code), coalesced stores.

#define NT 16384
#define NE 2048
#define NTH 256
#define NBLK 1024
#define WS_HALFS 163840   // 5*64*64*8 halfs per plane (h at 0, l at +WS_HALFS)

typedef _Float16 v8h __attribute__((ext_vector_type(8)));
typedef float    v4f __attribute__((ext_vector_type(4)));

__global__ __launch_bounds__(256, 1)
void prep(const float* __restrict__ gw, const float* __restrict__ ew,
          _Float16* __restrict__ wf)
{
    const int f = blockIdx.x * 256 + threadIdx.x;     // 0..163839, consecutive -> coalesced writes
    const int j  = f & 7;
    const int sl = (f >> 3) & 63;                     // slot = q*16 + m (lane order)
    const int ks = (f >> 9) & 63;                     // 32-float k-step
    const int g  = f >> 15;                           // gate tile 0..4
    const int q  = sl >> 4, m = sl & 15;
    const int gate = g * 16 + m;
    const int k = ks * 32 + q * 8 + j;
    float v = 0.f;
    if (gate < 64)      v = ew[gate * NE + k];
    else if (gate < 72) v = gw[(gate - 64) * NE + k];
    const _Float16 h = (_Float16)v;
    wf[f]            = h;
    wf[WS_HALFS + f] = (_Float16)((v - (float)h) * 2048.0f);
}

__global__ __launch_bounds__(NTH, 4)
void router(const float* __restrict__ x, const _Float16* __restrict__ wf,
            float* __restrict__ out)
{
    __shared__ __align__(16) char sm[20736];   // red[3][5][4][64] 15360 | la[16][84] 5376
    const int tid  = threadIdx.x;
    const int lane = tid & 63;
    const int w    = tid >> 6;                 // K-quarter 0..3
    const int t0   = blockIdx.x * 16;

    // x B-fragment: token = lane&15, k = ks*32 + (lane>>4)*8 + j  (proven layout)
    const float* xp = x + (size_t)(t0 + (lane & 15)) * NE + (lane >> 4) * 8;

    v4f accH[5], accC[5];
    #pragma unroll
    for (int g = 0; g < 5; ++g) { accH[g] = (v4f)(0.f); accC[g] = (v4f)(0.f); }

    float4 xr0, xr1;
    auto xload = [&](int s) {
        const float* p = xp + (size_t)(w * 16 + s) * 32;
        xr0 = *(const float4*)(p);
        xr1 = *(const float4*)(p + 4);
    };

    xload(0);
    for (int s = 0; s < 16; ++s) {
        // split current x regs -> Bh/Bl, then immediately prefetch next step into xr
        v8h Bh, Bl;
        {
            const float xv[8] = {xr0.x, xr0.y, xr0.z, xr0.w, xr1.x, xr1.y, xr1.z, xr1.w};
            #pragma unroll
            for (int j = 0; j < 8; ++j) {
                const _Float16 hh = (_Float16)xv[j];
                Bh[j] = hh;
                Bl[j] = (_Float16)((xv[j] - (float)hh) * 2048.0f);
            }
        }
        if (s + 1 < 16) xload(s + 1);

        const int ks = w * 16 + s;
        const _Float16* base = wf + ((size_t)ks * 64 + lane) * 8;
        #pragma unroll
        for (int g = 0; g < 5; ++g) {
            const v8h Ah = *(const v8h*)(base + g * 32768);
            const v8h Al = *(const v8h*)(base + g * 32768 + WS_HALFS);
            accH[g] = __builtin_amdgcn_mfma_f32_16x16x32_f16(Ah, Bh, accH[g], 0, 0, 0);
            accC[g] = __builtin_amdgcn_mfma_f32_16x16x32_f16(Ah, Bl, accC[g], 0, 0, 0);
            accC[g] = __builtin_amdgcn_mfma_f32_16x16x32_f16(Al, Bh, accC[g], 0, 0, 0);
        }
    }

    // ---- exact recombine + 4-way K-reduce ----
    float part[5][4];
    #pragma unroll
    for (int g = 0; g < 5; ++g)
        #pragma unroll
        for (int r = 0; r < 4; ++r)
            part[g][r] = accH[g][r] + accC[g][r] * (1.0f / 2048.0f);

    float* red = (float*)sm;                       // [wq-1][g][r][lane]
    if (w > 0) {
        #pragma unroll
        for (int g = 0; g < 5; ++g)
            #pragma unroll
            for (int r = 0; r < 4; ++r)
                red[(((w - 1) * 5 + g) * 4 + r) * 64 + lane] = part[g][r];
    }
    __syncthreads();
    float* la = (float*)(sm + 15360);              // [16 tokens][84]
    if (w == 0) {
        #pragma unroll
        for (int g = 0; g < 5; ++g)
            #pragma unroll
            for (int r = 0; r < 4; ++r) {
                float v = part[g][r]
                        + red[((0 * 5 + g) * 4 + r) * 64 + lane]
                        + red[((1 * 5 + g) * 4 + r) * 64 + lane]
                        + red[((2 * 5 + g) * 4 + r) * 64 + lane];
                const int gate  = g * 16 + (lane >> 4) * 4 + r;   // D row = gate
                const int token = lane & 15;                      // D col = token
                la[token * 84 + gate] = v;
            }
    }
    __syncthreads();

    // ---- per-token dual softmax + hierarchical mask (proven fp32 code), 4 tok/wave ----
    if (lane < 4) {
        const int token = w * 4 + lane;
        const float* lg = la + token * 84;          // [0..63]=experts, [64..71]=groups
        float* M  = (float*)sm + token * 64;        // overlays dead red [0,4096)
        float* Wn = (float*)(sm + 4096) + token * 64;

        float gpb[8];
        float gmax = lg[64];
        #pragma unroll
        for (int g = 1; g < 8; ++g) gmax = fmaxf(gmax, lg[64 + g]);
        float gsum = 0.f;
        #pragma unroll
        for (int g = 0; g < 8; ++g) { gpb[g] = __expf(lg[64 + g] - gmax); gsum += gpb[g]; }
        const float ginv = 1.f / gsum;

        float sel[64];
        float wsum = 0.f;
        #pragma unroll
        for (int g = 0; g < 8; ++g) {
            const float gp_ = gpb[g] * ginv;
            float emax = lg[g * 8];
            #pragma unroll
            for (int j = 1; j < 8; ++j) emax = fmaxf(emax, lg[g * 8 + j]);
            float ep[8]; float esum = 0.f;
            #pragma unroll
            for (int j = 0; j < 8; ++j) { ep[j] = __expf(lg[g * 8 + j] - emax); esum += ep[j]; }
            const float einv = 1.f / esum;
            const bool gm = gp_ >= 0.125f;
            #pragma unroll
            for (int j = 0; j < 8; ++j) {
                const float pe = ep[j] * einv;
                const bool v = gm && (pe >= 0.125f);
                const float ww = v ? gp_ * pe : 0.f;
                M[g * 8 + j] = v ? 1.f : 0.f;
                sel[g * 8 + j] = ww;
                wsum += ww;
            }
        }
        const float inv = 1.f / fmaxf(wsum, 1e-9f);
        #pragma unroll
        for (int e = 0; e < 64; ++e) Wn[e] = sel[e] * inv;
    }
    __syncthreads();

    // ---- coalesced stores: 16 tokens x 64 = 256 float4 per tensor ----
    const float4* M4 = (const float4*)sm;
    const float4* W4 = (const float4*)(sm + 4096);
    float4* o0 = (float4*)(out + (size_t)t0 * 64);
    float4* o1 = (float4*)(out + (size_t)NT * 64 + (size_t)t0 * 64);
    o0[tid] = M4[tid];
    o1[tid] = W4[tid];
}

extern "C" void kernel_launch(void* const* d_in, const int* in_sizes, int n_in,
                              void* d_out, int out_size, void* d_ws, size_t ws_size,
                              hipStream_t stream) {
    const float* x  = (const float*)d_in[0];
    const float* gw = (const float*)d_in[1];
    const float* ew = (const float*)d_in[2];
    float* out = (float*)d_out;
    _Float16* wf = (_Float16*)d_ws;
    (void)ws_size; (void)in_sizes; (void)n_in; (void)out_size;

    prep<<<dim3(640), dim3(256), 0, stream>>>(gw, ew, wf);
    router<<<dim3(NBLK), dim3(NTH), 0, stream>>>(x, wf, out);
}